// Round 2
// baseline (4647.173 us; speedup 1.0000x reference)
//
#include <hip/hip_runtime.h>

// ---------------- constants ----------------
#define BB    32
#define SS    512
#define DD    1024
#define HH_   16
#define DH    64
#define LL    4
#define DFF   2048
#define DMEM  512
#define NTOK  (BB * SS)          // 16384

typedef __attribute__((ext_vector_type(8))) short short8;
typedef __attribute__((ext_vector_type(4))) float f32x4;

__device__ __forceinline__ unsigned short f2bf(float x) {
    unsigned u = __float_as_uint(x);
    u = (u + 0x7FFFu + ((u >> 16) & 1u)) >> 16;   // RNE fp32->bf16
    return (unsigned short)u;
}
__device__ __forceinline__ float bf2f(unsigned short x) {
    return __uint_as_float(((unsigned)x) << 16);
}

// ---------------- h = x + PE -> bf16 residual stream ----------------
__global__ void add_pe_kernel(const float* __restrict__ x,
                              unsigned short* __restrict__ hb) {
    int idx = blockIdx.x * 256 + threadIdx.x;      // 16M elems
    int d = idx & (DD - 1);
    int t = idx >> 10;
    int s = t & (SS - 1);
    float freq = __expf((float)(d & ~1) * (-9.210340371976184f / (float)DD));
    float ang = (float)s * freq;
    float pe = (d & 1) ? cosf(ang) : sinf(ang);
    hb[idx] = f2bf(x[idx] + pe);
}

// ---------------- bf16 GEMM: C[M,N] = A[M,K] * W[N,K]^T + bias ----------------
// A is bf16; W is fp32 (converted to bf16 during LDS staging).
// 128x128 tile, BK=32, 256 threads (4 waves, each 64x64 = 4x4 MFMA 16x16x32)
template<bool RELU>
__global__ __launch_bounds__(256) void gemm_bt(
    const unsigned short* __restrict__ A, const float* __restrict__ Wf,
    const float* __restrict__ bias,
    float* __restrict__ Cf, unsigned short* __restrict__ Cb,
    int M, int N, int K)
{
    __shared__ __align__(16) unsigned short As[128 * 32];
    __shared__ __align__(16) unsigned short Bs[128 * 32];
    const int tid  = threadIdx.x;
    const int bm   = blockIdx.y, bn = blockIdx.x;
    const int w    = tid >> 6, lane = tid & 63;
    const int wm   = (w >> 1) * 64, wn = (w & 1) * 64;
    const int quad = lane >> 4, l16 = lane & 15;

    f32x4 acc[4][4];
    #pragma unroll
    for (int i = 0; i < 4; i++)
        #pragma unroll
        for (int j = 0; j < 4; j++) acc[i][j] = (f32x4){0.f, 0.f, 0.f, 0.f};

    for (int k0 = 0; k0 < K; k0 += 32) {
        __syncthreads();
        #pragma unroll
        for (int u = 0; u < 2; u++) {
            int c = tid * 2 + u;                 // 512 chunks of 8 elems
            int row = c >> 2, cc = (c & 3) * 8;
            // A: bf16 direct 16B copy
            *(uint4*)&As[row * 32 + cc] =
                *(const uint4*)&A[(size_t)(bm * 128 + row) * K + k0 + cc];
            // W: fp32 -> bf16 pack
            const float* wp = &Wf[(size_t)(bn * 128 + row) * K + k0 + cc];
            float4 w0 = *(const float4*)wp;
            float4 w1 = *(const float4*)(wp + 4);
            uint4 pk;
            pk.x = ((unsigned)f2bf(w0.y) << 16) | f2bf(w0.x);
            pk.y = ((unsigned)f2bf(w0.w) << 16) | f2bf(w0.z);
            pk.z = ((unsigned)f2bf(w1.y) << 16) | f2bf(w1.x);
            pk.w = ((unsigned)f2bf(w1.w) << 16) | f2bf(w1.z);
            *(uint4*)&Bs[row * 32 + cc] = pk;
        }
        __syncthreads();
        short8 af[4], bfr[4];
        #pragma unroll
        for (int i = 0; i < 4; i++)
            af[i] = *(const short8*)&As[(wm + i * 16 + l16) * 32 + quad * 8];
        #pragma unroll
        for (int j = 0; j < 4; j++)
            bfr[j] = *(const short8*)&Bs[(wn + j * 16 + l16) * 32 + quad * 8];
        #pragma unroll
        for (int i = 0; i < 4; i++)
            #pragma unroll
            for (int j = 0; j < 4; j++)
                acc[i][j] = __builtin_amdgcn_mfma_f32_16x16x32_bf16(af[i], bfr[j], acc[i][j], 0, 0, 0);
    }

    #pragma unroll
    for (int i = 0; i < 4; i++) {
        #pragma unroll
        for (int j = 0; j < 4; j++) {
            int col = bn * 128 + wn + j * 16 + l16;
            float bv = bias ? bias[col] : 0.f;
            f32x4 av = acc[i][j];
            #pragma unroll
            for (int r = 0; r < 4; r++) {
                int row = bm * 128 + wm + i * 16 + quad * 4 + r;
                float v = av[r] + bv;
                if (RELU) v = fmaxf(v, 0.f);
                size_t off = (size_t)row * N + col;
                if (Cf) Cf[off] = v;
                if (Cb) Cb[off] = f2bf(v);
            }
        }
    }
}

// ---------------- attention: one block per (b, h, 16-row q-tile) ----------------
// scores 16x512 in LDS (fp32), K/V streamed in 64-row tiles, deferred softmax norm
__global__ __launch_bounds__(256) void attn_kernel(const unsigned short* __restrict__ qkv,
                                                   unsigned short* __restrict__ ctx)
{
    __shared__ __align__(16) float sS[16 * 512];            // 32 KB scores/probs
    __shared__ __align__(16) unsigned short sKT[64 * 64];   // 8 KB K/V tile
    __shared__ __align__(16) unsigned short sQ[16 * 64];    // 2 KB
    __shared__ __align__(16) float sRed[256];
    __shared__ __align__(16) float sInv[16];

    const int tid  = threadIdx.x;
    const int blk  = blockIdx.x;
    const int qt   = blk & 31;                // 32 q-tiles of 16 rows
    const int hh   = (blk >> 5) & 15;
    const int b    = blk >> 9;
    const int w    = tid >> 6, lane = tid & 63;
    const int quad = lane >> 4, l16 = lane & 15;
    const size_t rowbase = (size_t)b * SS;
    const int LDQ = 3 * DD;

    // load Q tile: 16 rows x 64 = 128 chunks of 8 bf16
    if (tid < 128) {
        int r = tid >> 3, cc = (tid & 7) * 8;
        *(uint4*)&sQ[r * 64 + cc] =
            *(const uint4*)&qkv[(rowbase + qt * 16 + r) * LDQ + hh * 64 + cc];
    }
    __syncthreads();
    short8 qa0 = *(const short8*)&sQ[l16 * 64 + quad * 8];
    short8 qa1 = *(const short8*)&sQ[l16 * 64 + 32 + quad * 8];

    // ---- phase 1: scores S[16,512] = Q K^T * 0.125 ----
    for (int kt = 0; kt < 8; kt++) {
        __syncthreads();
        #pragma unroll
        for (int u = 0; u < 2; u++) {
            int c = tid * 2 + u;               // 512 chunks
            int r = c >> 3, cc = (c & 7) * 8;
            *(uint4*)&sKT[r * 64 + cc] =
                *(const uint4*)&qkv[(rowbase + kt * 64 + r) * LDQ + DD + hh * 64 + cc];
        }
        __syncthreads();
        f32x4 a = (f32x4){0.f, 0.f, 0.f, 0.f};
        short8 kb0 = *(const short8*)&sKT[(w * 16 + l16) * 64 + quad * 8];
        short8 kb1 = *(const short8*)&sKT[(w * 16 + l16) * 64 + 32 + quad * 8];
        a = __builtin_amdgcn_mfma_f32_16x16x32_bf16(qa0, kb0, a, 0, 0, 0);
        a = __builtin_amdgcn_mfma_f32_16x16x32_bf16(qa1, kb1, a, 0, 0, 0);
        #pragma unroll
        for (int r = 0; r < 4; r++)
            sS[(quad * 4 + r) * 512 + kt * 64 + w * 16 + l16] = a[r] * 0.125f;
    }
    __syncthreads();

    // ---- phase 2: softmax (unnormalized exp; keep 1/sum) ----
    {
        int row = tid >> 4, sub = tid & 15;
        float* srow = sS + row * 512;
        float mx = -1e30f;
        for (int i = sub; i < 512; i += 16) mx = fmaxf(mx, srow[i]);
        sRed[row * 16 + sub] = mx;
        __syncthreads();
        mx = sRed[row * 16];
        #pragma unroll
        for (int i = 1; i < 16; i++) mx = fmaxf(mx, sRed[row * 16 + i]);
        float sum = 0.f;
        for (int i = sub; i < 512; i += 16) {
            float e = __expf(srow[i] - mx);
            srow[i] = e;
            sum += e;
        }
        __syncthreads();
        sRed[row * 16 + sub] = sum;
        __syncthreads();
        sum = 0.f;
        #pragma unroll
        for (int i = 0; i < 16; i++) sum += sRed[row * 16 + i];
        if (sub == 0) sInv[row] = 1.f / sum;
    }

    // ---- phase 3: ctx[16,64] = P V ; wave w owns 16-col n-tile ----
    f32x4 o = (f32x4){0.f, 0.f, 0.f, 0.f};
    for (int kt = 0; kt < 8; kt++) {
        __syncthreads();
        #pragma unroll
        for (int u = 0; u < 2; u++) {
            int c = tid * 2 + u;
            int r = c >> 3, cc = (c & 7) * 8;
            *(uint4*)&sKT[r * 64 + cc] =
                *(const uint4*)&qkv[(rowbase + kt * 64 + r) * LDQ + 2 * DD + hh * 64 + cc];
        }
        __syncthreads();
        #pragma unroll
        for (int kk = 0; kk < 2; kk++) {
            int k0 = kt * 64 + kk * 32;
            short8 vb, pa;
            short* vbp = (short*)&vb;
            short* pap = (short*)&pa;
            #pragma unroll
            for (int j = 0; j < 8; j++) {
                vbp[j] = (short)sKT[(kk * 32 + quad * 8 + j) * 64 + w * 16 + l16];
                pap[j] = (short)f2bf(sS[l16 * 512 + k0 + quad * 8 + j]);
            }
            o = __builtin_amdgcn_mfma_f32_16x16x32_bf16(pa, vb, o, 0, 0, 0);
        }
    }
    #pragma unroll
    for (int r = 0; r < 4; r++) {
        int row = quad * 4 + r;
        int col = hh * 64 + w * 16 + l16;
        ctx[(rowbase + qt * 16 + row) * DD + col] = f2bf(o[r] * sInv[row]);
    }
}

// ---------------- layernorm (+ optional residual add) on bf16 stream ----------------
__global__ __launch_bounds__(256) void ln_kernel(
    unsigned short* __restrict__ hb, const unsigned short* __restrict__ add,
    const float* __restrict__ g, const float* __restrict__ beta)
{
    __shared__ float sred[4];
    const int t = blockIdx.x, tid = threadIdx.x;
    const size_t base = (size_t)t * DD;
    float x[4];
    float s = 0.f;
    #pragma unroll
    for (int i = 0; i < 4; i++) {
        int d = tid + i * 256;
        float v = bf2f(hb[base + d]);
        if (add) v += bf2f(add[base + d]);
        x[i] = v;
        s += v;
    }
    #pragma unroll
    for (int off = 32; off > 0; off >>= 1) s += __shfl_down(s, off);
    if ((tid & 63) == 0) sred[tid >> 6] = s;
    __syncthreads();
    float mu = (sred[0] + sred[1] + sred[2] + sred[3]) * (1.f / DD);
    __syncthreads();
    float vs = 0.f;
    #pragma unroll
    for (int i = 0; i < 4; i++) { float dx = x[i] - mu; vs += dx * dx; }
    #pragma unroll
    for (int off = 32; off > 0; off >>= 1) vs += __shfl_down(vs, off);
    if ((tid & 63) == 0) sred[tid >> 6] = vs;
    __syncthreads();
    float var = (sred[0] + sred[1] + sred[2] + sred[3]) * (1.f / DD);
    float inv = rsqrtf(var + 1e-5f);
    #pragma unroll
    for (int i = 0; i < 4; i++) {
        int d = tid + i * 256;
        float y = (x[i] - mu) * inv * g[d] + beta[d];
        hb[base + d] = f2bf(y);
    }
}

// ---------------- launcher ----------------
extern "C" void kernel_launch(void* const* d_in, const int* in_sizes, int n_in,
                              void* d_out, int out_size, void* d_ws, size_t ws_size,
                              hipStream_t stream)
{
    const float* x    = (const float*)d_in[0];
    const float* Wqkv = (const float*)d_in[1];
    const float* bqkv = (const float*)d_in[2];
    const float* Wo   = (const float*)d_in[3];
    const float* bo   = (const float*)d_in[4];
    const float* W1   = (const float*)d_in[5];
    const float* b1   = (const float*)d_in[6];
    const float* W2   = (const float*)d_in[7];
    const float* b2   = (const float*)d_in[8];
    const float* ln1g = (const float*)d_in[9];
    const float* ln1b = (const float*)d_in[10];
    const float* ln2g = (const float*)d_in[11];
    const float* ln2b = (const float*)d_in[12];
    const float* nfg  = (const float*)d_in[13];
    const float* nfb  = (const float*)d_in[14];
    const float* Wout = (const float*)d_in[15];
    const float* bout = (const float*)d_in[16];
    float* out = (float*)d_out;

    // workspace: 160 MB total
    char* ws = (char*)d_ws;
    const size_t MB = 1024 * 1024;
    unsigned short* hb   = (unsigned short*)(ws + 0 * MB);    // 32 MB residual stream (bf16)
    unsigned short* qkvb = (unsigned short*)(ws + 32 * MB);   // 96 MB qkv; first 64 MB reused as ff1-out
    unsigned short* tmpb = (unsigned short*)(ws + 96 * MB);   // 32 MB sa/ff2-out (overlays tail of qkvb)
    unsigned short* ctxb = (unsigned short*)(ws + 128 * MB);  // 32 MB

    add_pe_kernel<<<NTOK * DD / 256, 256, 0, stream>>>(x, hb);

    for (int l = 0; l < LL; l++) {
        // qkv = hb @ Wqkv^T + bqkv
        gemm_bt<false><<<dim3(3 * DD / 128, NTOK / 128), 256, 0, stream>>>(
            hb, Wqkv + (size_t)l * 3 * DD * DD, bqkv + l * 3 * DD,
            nullptr, qkvb, NTOK, 3 * DD, DD);
        attn_kernel<<<BB * HH_ * (SS / 16), 256, 0, stream>>>(qkvb, ctxb);
        // sa = ctx @ Wo^T + bo   (qkvb dead now; tmpb overlays its tail)
        gemm_bt<false><<<dim3(DD / 128, NTOK / 128), 256, 0, stream>>>(
            ctxb, Wo + (size_t)l * DD * DD, bo + l * DD,
            nullptr, tmpb, NTOK, DD, DD);
        ln_kernel<<<NTOK, 256, 0, stream>>>(hb, tmpb, ln1g + l * DD, ln1b + l * DD);
        // ff1 = relu(hb @ W1^T + b1) -> qkvb[0:64MB]
        gemm_bt<true><<<dim3(DFF / 128, NTOK / 128), 256, 0, stream>>>(
            hb, W1 + (size_t)l * DFF * DD, b1 + l * DFF,
            nullptr, qkvb, NTOK, DFF, DD);
        // ff2 = ff1 @ W2^T + b2 -> tmpb (disjoint from ff1's 64 MB)
        gemm_bt<false><<<dim3(DD / 128, NTOK / 128), 256, 0, stream>>>(
            qkvb, W2 + (size_t)l * DD * DFF, b2 + l * DD,
            nullptr, tmpb, NTOK, DD, DFF);
        ln_kernel<<<NTOK, 256, 0, stream>>>(hb, tmpb, ln2g + l * DD, ln2b + l * DD);
    }
    ln_kernel<<<NTOK, 256, 0, stream>>>(hb, nullptr, nfg, nfb);
    // out = hb @ Wout^T + bout
    gemm_bt<false><<<dim3(DMEM / 128, NTOK / 128), 256, 0, stream>>>(
        hb, Wout, bout, out, nullptr, NTOK, DMEM, DD);
}

// Round 4
// 2892.756 us; speedup vs baseline: 1.6065x; 1.6065x over previous
//
#include <hip/hip_runtime.h>

// ---------------- constants ----------------
#define BB    32
#define SS    512
#define DD    1024
#define HH_   16
#define DH    64
#define LL    4
#define DFF   2048
#define DMEM  512
#define NTOK  (BB * SS)          // 16384
#define SPLD  72                 // padded LDS row stride (u16) for attention tiles

typedef __attribute__((ext_vector_type(8))) short short8;
typedef __attribute__((ext_vector_type(4))) float f32x4;

__device__ __forceinline__ unsigned short f2bf(float x) {
    unsigned u = __float_as_uint(x);
    u = (u + 0x7FFFu + ((u >> 16) & 1u)) >> 16;   // RNE fp32->bf16
    return (unsigned short)u;
}
__device__ __forceinline__ float bf2f(unsigned short x) {
    return __uint_as_float(((unsigned)x) << 16);
}

// async global->LDS, 16 bytes per lane; LDS dest = wave-uniform base + lane*16
__device__ __forceinline__ void async16(const unsigned short* g, unsigned short* l) {
    __builtin_amdgcn_global_load_lds(
        (__attribute__((address_space(1))) void*)g,
        (__attribute__((address_space(3))) void*)l,
        16, 0, 0);
}

// ---------------- fp32 -> bf16 convert ----------------
__global__ void cvt_bf16(const float* __restrict__ in, unsigned short* __restrict__ out, int n) {
    int i = blockIdx.x * 256 + threadIdx.x;
    if (i < n) out[i] = f2bf(in[i]);
}

// ---------------- h = x + PE -> bf16 residual stream ----------------
__global__ void add_pe_kernel(const float* __restrict__ x,
                              unsigned short* __restrict__ hb) {
    int idx = blockIdx.x * 256 + threadIdx.x;      // 16M elems
    int d = idx & (DD - 1);
    int t = idx >> 10;
    int s = t & (SS - 1);
    float freq = __expf((float)(d & ~1) * (-9.210340371976184f / (float)DD));
    float ang = (float)s * freq;
    float pe = (d & 1) ? cosf(ang) : sinf(ang);
    hb[idx] = f2bf(x[idx] + pe);
}

// ---------------- bf16 GEMM: C[M,N] = A[M,K] * W[N,K]^T + bias ----------------
// 128x128 tile, BK=32, 256 threads (4 waves, each 64x64 = 4x4 MFMA 16x16x32)
// WPRE: W already bf16 -> both operands staged via global_load_lds (m97 structure)
template<bool RELU, bool WPRE>
__global__ __launch_bounds__(256) void gemm_bt(
    const unsigned short* __restrict__ A,
    const unsigned short* __restrict__ Wb,
    const float* __restrict__ Wf,
    const float* __restrict__ bias,
    float* __restrict__ Cf, unsigned short* __restrict__ Cb,
    int M, int N, int K)
{
    __shared__ __align__(16) unsigned short As[128 * 32];
    __shared__ __align__(16) unsigned short Bs[128 * 32];
    const int tid  = threadIdx.x;
    const int bm   = blockIdx.y, bn = blockIdx.x;
    const int w    = tid >> 6, lane = tid & 63;
    const int wm   = (w >> 1) * 64, wn = (w & 1) * 64;
    const int quad = lane >> 4, l16 = lane & 15;

    f32x4 acc[4][4];
    #pragma unroll
    for (int i = 0; i < 4; i++)
        #pragma unroll
        for (int j = 0; j < 4; j++) acc[i][j] = (f32x4){0.f, 0.f, 0.f, 0.f};

    const int rlane = lane >> 2, clane = (lane & 3) * 8;

    for (int k0 = 0; k0 < K; k0 += 32) {
        __syncthreads();
        if (WPRE) {
            // one async16 call = 64 lanes x 16B = 16 rows of 32 u16.
            // 128-row tile = 8 segments per operand -> 2 per wave per operand.
            #pragma unroll
            for (int i = 0; i < 2; i++) {
                int j = w * 2 + i;          // j in 0..7
                async16(&A [(size_t)(bm * 128 + j * 16 + rlane) * K + k0 + clane], &As[j * 512]);
                async16(&Wb[(size_t)(bn * 128 + j * 16 + rlane) * K + k0 + clane], &Bs[j * 512]);
            }
        } else {
            #pragma unroll
            for (int u = 0; u < 2; u++) {
                int c = tid * 2 + u;                 // 512 chunks of 8 elems
                int row = c >> 2, cc = (c & 3) * 8;
                *(uint4*)&As[row * 32 + cc] =
                    *(const uint4*)&A[(size_t)(bm * 128 + row) * K + k0 + cc];
                const float* wp = &Wf[(size_t)(bn * 128 + row) * K + k0 + cc];
                float4 w0 = *(const float4*)wp;
                float4 w1 = *(const float4*)(wp + 4);
                uint4 pk;
                pk.x = ((unsigned)f2bf(w0.y) << 16) | f2bf(w0.x);
                pk.y = ((unsigned)f2bf(w0.w) << 16) | f2bf(w0.z);
                pk.z = ((unsigned)f2bf(w1.y) << 16) | f2bf(w1.x);
                pk.w = ((unsigned)f2bf(w1.w) << 16) | f2bf(w1.z);
                *(uint4*)&Bs[row * 32 + cc] = pk;
            }
        }
        __syncthreads();
        short8 af[4], bfr[4];
        #pragma unroll
        for (int i = 0; i < 4; i++)
            af[i] = *(const short8*)&As[(wm + i * 16 + l16) * 32 + quad * 8];
        #pragma unroll
        for (int j = 0; j < 4; j++)
            bfr[j] = *(const short8*)&Bs[(wn + j * 16 + l16) * 32 + quad * 8];
        #pragma unroll
        for (int i = 0; i < 4; i++)
            #pragma unroll
            for (int j = 0; j < 4; j++)
                acc[i][j] = __builtin_amdgcn_mfma_f32_16x16x32_bf16(af[i], bfr[j], acc[i][j], 0, 0, 0);
    }

    #pragma unroll
    for (int i = 0; i < 4; i++) {
        #pragma unroll
        for (int j = 0; j < 4; j++) {
            int col = bn * 128 + wn + j * 16 + l16;
            float bv = bias ? bias[col] : 0.f;
            f32x4 av = acc[i][j];
            #pragma unroll
            for (int r = 0; r < 4; r++) {
                int row = bm * 128 + wm + i * 16 + quad * 4 + r;
                float v = av[r] + bv;
                if (RELU) v = fmaxf(v, 0.f);
                size_t off = (size_t)row * N + col;
                if (Cf) Cf[off] = v;
                if (Cb) Cb[off] = f2bf(v);
            }
        }
    }
}

// ---------------- attention: flash-style, block per (b, h, 64-row q-tile) ----------------
// online softmax in registers; P through wave-private LDS; V transposed on stage
__global__ __launch_bounds__(256) void attn_kernel(const unsigned short* __restrict__ qkv,
                                                   unsigned short* __restrict__ ctx)
{
    __shared__ __align__(16) unsigned short sQ [64 * SPLD];  // 9 KB  [q][d], Q*0.125
    __shared__ __align__(16) unsigned short sK [64 * SPLD];  // 9 KB  [t][d]
    __shared__ __align__(16) unsigned short sVt[64 * SPLD];  // 9 KB  [d][t]
    __shared__ __align__(16) unsigned short sP [64 * SPLD];  // 9 KB  [q][t] wave-private rows

    const int tid  = threadIdx.x;
    const int blk  = blockIdx.x;
    const int qt   = blk & 7;                 // 8 q-tiles of 64 rows
    const int hh   = (blk >> 3) & 15;
    const int b    = blk >> 7;
    const int w    = tid >> 6, lane = tid & 63;
    const int quad = lane >> 4, l16 = lane & 15;
    const size_t rowbase = (size_t)b * SS;
    const int LDQ = 3 * DD;

    // ---- stage Q tile 64x64, scaled by 1/8 ----
    #pragma unroll
    for (int u = 0; u < 2; u++) {
        int c = tid * 2 + u;                  // 512 chunks of 8
        int r = c >> 3, cc = (c & 7) * 8;
        uint4 q4 = *(const uint4*)&qkv[(rowbase + qt * 64 + r) * LDQ + hh * 64 + cc];
        unsigned short* qs = (unsigned short*)&q4;
        uint4 o4;
        unsigned short* os = (unsigned short*)&o4;
        #pragma unroll
        for (int e = 0; e < 8; e++) os[e] = f2bf(bf2f(qs[e]) * 0.125f);
        *(uint4*)&sQ[r * SPLD + cc] = o4;
    }
    __syncthreads();

    // Q A-frags for this wave's 16 rows (reused across all k-tiles)
    short8 qf[2];
    #pragma unroll
    for (int kk = 0; kk < 2; kk++)
        qf[kk] = *(const short8*)&sQ[(w * 16 + l16) * SPLD + kk * 32 + quad * 8];

    float m_i[4], l_i[4];
    f32x4 o[4];
    #pragma unroll
    for (int r = 0; r < 4; r++) { m_i[r] = -1e30f; l_i[r] = 0.f; }
    #pragma unroll
    for (int nt = 0; nt < 4; nt++) o[nt] = (f32x4){0.f, 0.f, 0.f, 0.f};

    for (int kt = 0; kt < 8; kt++) {
        __syncthreads();
        // ---- stage K tile [t][d] and V tile transposed [d][t] ----
        #pragma unroll
        for (int u = 0; u < 2; u++) {
            int c = tid * 2 + u;
            int r = c >> 3, cc = (c & 7) * 8;
            const size_t src = (rowbase + kt * 64 + r) * (size_t)LDQ + hh * 64 + cc;
            *(uint4*)&sK[r * SPLD + cc] = *(const uint4*)&qkv[src + DD];
            uint4 v4 = *(const uint4*)&qkv[src + 2 * DD];
            unsigned short* vs = (unsigned short*)&v4;
            #pragma unroll
            for (int e = 0; e < 8; e++) sVt[(cc + e) * SPLD + r] = vs[e];
        }
        __syncthreads();

        // ---- S block: 16q x 64t via 8 MFMAs ----
        f32x4 s[4];
        #pragma unroll
        for (int ct = 0; ct < 4; ct++) s[ct] = (f32x4){0.f, 0.f, 0.f, 0.f};
        #pragma unroll
        for (int kk = 0; kk < 2; kk++)
            #pragma unroll
            for (int ct = 0; ct < 4; ct++) {
                short8 kb = *(const short8*)&sK[(ct * 16 + l16) * SPLD + kk * 32 + quad * 8];
                s[ct] = __builtin_amdgcn_mfma_f32_16x16x32_bf16(qf[kk], kb, s[ct], 0, 0, 0);
            }

        // ---- online softmax (rows = quad*4+r, cols = l16 across 16 lanes) ----
        float mb[4], rs[4], al[4];
        #pragma unroll
        for (int r = 0; r < 4; r++) {
            mb[r] = fmaxf(fmaxf(s[0][r], s[1][r]), fmaxf(s[2][r], s[3][r]));
            #pragma unroll
            for (int msk = 1; msk < 16; msk <<= 1)
                mb[r] = fmaxf(mb[r], __shfl_xor(mb[r], msk));
            float mn = fmaxf(m_i[r], mb[r]);
            al[r] = __expf(m_i[r] - mn);
            m_i[r] = mn;
            rs[r] = 0.f;
        }
        #pragma unroll
        for (int ct = 0; ct < 4; ct++)
            #pragma unroll
            for (int r = 0; r < 4; r++) {
                float p = __expf(s[ct][r] - m_i[r]);
                s[ct][r] = p;
                rs[r] += p;
            }
        #pragma unroll
        for (int r = 0; r < 4; r++) {
            #pragma unroll
            for (int msk = 1; msk < 16; msk <<= 1)
                rs[r] += __shfl_xor(rs[r], msk);
            l_i[r] = l_i[r] * al[r] + rs[r];
        }
        #pragma unroll
        for (int nt = 0; nt < 4; nt++)
            #pragma unroll
            for (int r = 0; r < 4; r++) o[nt][r] *= al[r];

        // ---- P (C-layout) -> LDS bf16 (wave-private 16 rows) ----
        #pragma unroll
        for (int ct = 0; ct < 4; ct++)
            #pragma unroll
            for (int r = 0; r < 4; r++)
                sP[(w * 16 + quad * 4 + r) * SPLD + ct * 16 + l16] = f2bf(s[ct][r]);

        // ---- PV: 8 MFMAs, A = P (A-layout rows l16), B = V^T ----
        #pragma unroll
        for (int kk = 0; kk < 2; kk++) {
            short8 pa = *(const short8*)&sP[(w * 16 + l16) * SPLD + kk * 32 + quad * 8];
            #pragma unroll
            for (int nt = 0; nt < 4; nt++) {
                short8 vb = *(const short8*)&sVt[(nt * 16 + l16) * SPLD + kk * 32 + quad * 8];
                o[nt] = __builtin_amdgcn_mfma_f32_16x16x32_bf16(pa, vb, o[nt], 0, 0, 0);
            }
        }
    }

    // ---- epilogue: normalize by 1/l, write ctx ----
    float inv[4];
    #pragma unroll
    for (int r = 0; r < 4; r++) inv[r] = 1.f / l_i[r];
    #pragma unroll
    for (int nt = 0; nt < 4; nt++)
        #pragma unroll
        for (int r = 0; r < 4; r++)
            ctx[(rowbase + qt * 64 + w * 16 + quad * 4 + r) * DD + hh * 64 + nt * 16 + l16] =
                f2bf(o[nt][r] * inv[r]);
}

// ---------------- layernorm (+ optional residual add) on bf16 stream ----------------
__global__ __launch_bounds__(256) void ln_kernel(
    unsigned short* __restrict__ hb, const unsigned short* __restrict__ add,
    const float* __restrict__ g, const float* __restrict__ beta)
{
    __shared__ float sred[4];
    const int t = blockIdx.x, tid = threadIdx.x;
    const size_t base = (size_t)t * DD;
    float x[4];
    float s = 0.f;
    #pragma unroll
    for (int i = 0; i < 4; i++) {
        int d = tid + i * 256;
        float v = bf2f(hb[base + d]);
        if (add) v += bf2f(add[base + d]);
        x[i] = v;
        s += v;
    }
    #pragma unroll
    for (int off = 32; off > 0; off >>= 1) s += __shfl_down(s, off);
    if ((tid & 63) == 0) sred[tid >> 6] = s;
    __syncthreads();
    float mu = (sred[0] + sred[1] + sred[2] + sred[3]) * (1.f / DD);
    __syncthreads();
    float vs = 0.f;
    #pragma unroll
    for (int i = 0; i < 4; i++) { float dx = x[i] - mu; vs += dx * dx; }
    #pragma unroll
    for (int off = 32; off > 0; off >>= 1) vs += __shfl_down(vs, off);
    if ((tid & 63) == 0) sred[tid >> 6] = vs;
    __syncthreads();
    float var = (sred[0] + sred[1] + sred[2] + sred[3]) * (1.f / DD);
    float inv = rsqrtf(var + 1e-5f);
    #pragma unroll
    for (int i = 0; i < 4; i++) {
        int d = tid + i * 256;
        float y = (x[i] - mu) * inv * g[d] + beta[d];
        hb[base + d] = f2bf(y);
    }
}

// ---------------- host-side GEMM dispatch helper ----------------
static void launch_gemm(bool relu, bool pre, const unsigned short* A,
                        const unsigned short* Wb, const float* Wf, const float* bias,
                        float* Cf, unsigned short* Cb, int M, int N, int K, hipStream_t s)
{
    dim3 g(N / 128, M / 128);
    if (pre) {
        if (relu) gemm_bt<true,  true ><<<g, 256, 0, s>>>(A, Wb, nullptr, bias, Cf, Cb, M, N, K);
        else      gemm_bt<false, true ><<<g, 256, 0, s>>>(A, Wb, nullptr, bias, Cf, Cb, M, N, K);
    } else {
        if (relu) gemm_bt<true,  false><<<g, 256, 0, s>>>(A, nullptr, Wf, bias, Cf, Cb, M, N, K);
        else      gemm_bt<false, false><<<g, 256, 0, s>>>(A, nullptr, Wf, bias, Cf, Cb, M, N, K);
    }
}

// ---------------- launcher ----------------
extern "C" void kernel_launch(void* const* d_in, const int* in_sizes, int n_in,
                              void* d_out, int out_size, void* d_ws, size_t ws_size,
                              hipStream_t stream)
{
    const float* x    = (const float*)d_in[0];
    const float* Wqkv = (const float*)d_in[1];
    const float* bqkv = (const float*)d_in[2];
    const float* Wo   = (const float*)d_in[3];
    const float* bo   = (const float*)d_in[4];
    const float* W1   = (const float*)d_in[5];
    const float* b1   = (const float*)d_in[6];
    const float* W2   = (const float*)d_in[7];
    const float* b2   = (const float*)d_in[8];
    const float* ln1g = (const float*)d_in[9];
    const float* ln1b = (const float*)d_in[10];
    const float* ln2g = (const float*)d_in[11];
    const float* ln2b = (const float*)d_in[12];
    const float* nfg  = (const float*)d_in[13];
    const float* nfb  = (const float*)d_in[14];
    const float* Wout = (const float*)d_in[15];
    const float* bout = (const float*)d_in[16];
    float* out = (float*)d_out;

    char* ws = (char*)d_ws;
    const size_t MB = 1024 * 1024;
    unsigned short* hb    = (unsigned short*)(ws + 0 * MB);    // 32 MB residual stream
    unsigned short* qkvb  = (unsigned short*)(ws + 32 * MB);   // 96 MB qkv; first 64 MB reused as ff1-out
    unsigned short* tmpb  = (unsigned short*)(ws + 96 * MB);   // 32 MB sa/ff2-out
    unsigned short* ctxb  = (unsigned short*)(ws + 128 * MB);  // 32 MB
    unsigned short* WqkvB = (unsigned short*)(ws + 160 * MB);  // 24 MB
    unsigned short* W1B   = (unsigned short*)(ws + 184 * MB);  // 16 MB
    unsigned short* W2B   = (unsigned short*)(ws + 200 * MB);  // 16 MB
    unsigned short* WoB   = (unsigned short*)(ws + 216 * MB);  //  8 MB
    unsigned short* WoutB = (unsigned short*)(ws + 224 * MB);  //  1 MB

    const bool pre = ws_size >= 225 * MB;
    if (pre) {
        cvt_bf16<<<(LL * 3 * DD * DD + 255) / 256, 256, 0, stream>>>(Wqkv, WqkvB, LL * 3 * DD * DD);
        cvt_bf16<<<(LL * DFF * DD + 255) / 256, 256, 0, stream>>>(W1, W1B, LL * DFF * DD);
        cvt_bf16<<<(LL * DD * DFF + 255) / 256, 256, 0, stream>>>(W2, W2B, LL * DD * DFF);
        cvt_bf16<<<(LL * DD * DD + 255) / 256, 256, 0, stream>>>(Wo, WoB, LL * DD * DD);
        cvt_bf16<<<(DMEM * DD + 255) / 256, 256, 0, stream>>>(Wout, WoutB, DMEM * DD);
    }

    add_pe_kernel<<<NTOK * DD / 256, 256, 0, stream>>>(x, hb);

    for (int l = 0; l < LL; l++) {
        launch_gemm(false, pre, hb, WqkvB + (size_t)l * 3 * DD * DD,
                    Wqkv + (size_t)l * 3 * DD * DD, bqkv + l * 3 * DD,
                    nullptr, qkvb, NTOK, 3 * DD, DD, stream);
        attn_kernel<<<BB * HH_ * 8, 256, 0, stream>>>(qkvb, ctxb);
        launch_gemm(false, pre, ctxb, WoB + (size_t)l * DD * DD,
                    Wo + (size_t)l * DD * DD, bo + l * DD,
                    nullptr, tmpb, NTOK, DD, DD, stream);
        ln_kernel<<<NTOK, 256, 0, stream>>>(hb, tmpb, ln1g + l * DD, ln1b + l * DD);
        launch_gemm(true, pre, hb, W1B + (size_t)l * DFF * DD,
                    W1 + (size_t)l * DFF * DD, b1 + l * DFF,
                    nullptr, qkvb, NTOK, DFF, DD, stream);
        launch_gemm(false, pre, qkvb, W2B + (size_t)l * DD * DFF,
                    W2 + (size_t)l * DD * DFF, b2 + l * DD,
                    nullptr, tmpb, NTOK, DD, DFF, stream);
        ln_kernel<<<NTOK, 256, 0, stream>>>(hb, tmpb, ln2g + l * DD, ln2b + l * DD);
    }
    ln_kernel<<<NTOK, 256, 0, stream>>>(hb, nullptr, nfg, nfb);
    launch_gemm(false, pre, hb, WoutB, Wout, bout, out, nullptr, NTOK, DMEM, DD, stream);
}